// Round 1
// 272.205 us; speedup vs baseline: 1.1535x; 1.1535x over previous
//
#include <hip/hip_runtime.h>
#include <math.h>

#define BB 16
#define TT 4096
#define CC 128

// Chunked scan: L-sized output chunks, W-step cold-start warmup (proven
// R7/R8/R9 structure: absmax bit-identical 0.0625 at W=512/384/96; W=48
// keeps >2x empirical margin).
//
// R10 change: G=4 states per thread. The R9 kernel was LDS-read-throughput
// bound: 256 ds_read_b128/CU-step x 12cyc = 3072 of the 3510 measured
// cycles/step (e-broadcast reads deliver only 64B distinct per 1024B op).
// Each thread now dots the SAME 8 e-float4 reads against 4 pf rows
// (register reuse) -> LDS read ops per chain-step 64 -> 16. Block = 128
// threads (2 waves); grid 1024 blocks = 4 blocks/CU = 2 waves/SIMD, so
// pf's 128 VGPRs fit (launch_bounds(128,2) caps at 256).
// Quarter-combine moved from ds_swizzle (LDS pipe) to DPP quad-perm adds
// (VALU). Scale fixup is now 1 exp/thread (each q-chunk has exactly one
// producer wave: q<2 -> wave0, q>=2 -> wave1).
#define LCH 128
#define WCH 48
#define NCH (TT / LCH)   // 32 chunks per chain

// Padded e-chunk stride: 36 floats (144 B) staggers the 4 broadcast read
// addresses across banks 0/4/8/12 (R6->R7: conflicts 1.28e8 -> 0).
#define EST 36

typedef float f2 __attribute__((ext_vector_type(2)));

// ---------------------------------------------------------------------------
// ws layout (floats):
//   [0,            CC*CC)              P   (row-major, softmax(log_trans) rows)
//   [CC*CC,        2*CC*CC)            PT  (transpose of P)
//   [2*CC*CC,      2*CC*CC + BB*TT*CC) beta
// ---------------------------------------------------------------------------

__device__ __forceinline__ float wave_reduce_max(float v) {
#pragma unroll
    for (int o = 1; o < 64; o <<= 1) v = fmaxf(v, __shfl_xor(v, o, 64));
    return v;
}
__device__ __forceinline__ float wave_reduce_sum(float v) {
#pragma unroll
    for (int o = 1; o < 64; o <<= 1) v += __shfl_xor(v, o, 64);
    return v;
}

// LDS-only barrier: skip the compiler's conservative s_waitcnt vmcnt(0)
// before s_barrier so global prefetch/stores stay in flight.
__device__ __forceinline__ void lds_barrier() {
    __asm__ __volatile__("s_waitcnt lgkmcnt(0)" ::: "memory");
    __builtin_amdgcn_s_barrier();
}

// Quad-perm butterfly add via DPP: cross-lane xor over lane bits 0-1 on the
// VALU pipe (replaces two ds_swizzle round-trips on the per-step critical
// path). 0xB1 = quad_perm(1,0,3,2) (xor 1), 0x4E = quad_perm(2,3,0,1) (xor 2).
template <int CTRL>
__device__ __forceinline__ float qadd(float v) {
    int o = __builtin_amdgcn_update_dpp(0, __float_as_int(v), CTRL, 0xF, 0xF, true);
    return v + __int_as_float(o);
}

// ---------------------------------------------------------------------------
// Prep: P = exp(log_softmax(log_trans, axis=1)); also PT = P^T.
// ---------------------------------------------------------------------------
__global__ __launch_bounds__(CC) void prep_kernel(const float* __restrict__ lt,
                                                  float* __restrict__ P,
                                                  float* __restrict__ PT) {
    const int r  = blockIdx.x;
    const int j  = threadIdx.x;
    const int wv = j >> 6;
    __shared__ float sm[2];

    float x = lt[r * CC + j];
    float m = wave_reduce_max(x);
    if ((j & 63) == 0) sm[wv] = m;
    __syncthreads();
    m = fmaxf(sm[0], sm[1]);
    __syncthreads();
    float e = __expf(x - m);
    float s = wave_reduce_sum(e);
    if ((j & 63) == 0) sm[wv] = s;
    __syncthreads();
    s = sm[0] + sm[1];
    float p = e / s;
    P[r * CC + j]  = p;
    PT[j * CC + r] = p;
}

// ---------------------------------------------------------------------------
// Chunked scan, ONE barrier per step.
// Grid = 2*BB*NCH blocks of 128 threads (2 waves).
//   id < BB*NCH  : forward chunk  (alpha -> d_out)
//   id >= BB*NCH : backward chunk (beta  -> ws)
// Thread t: quarter q = t&3 (i-range [32q,32q+32)), group g = t>>2 owning
// states 4g..4g+3. pf = 4 rows x 16 f2 = 128 VGPRs (static indices only).
// The 4 q-copies of a group are consecutive lanes -> DPP quad combine.
// e stored padded: group g at ebuf[(g>>3)*EST + (g&7)*4] (float4 write by
// q==0). ebuf/wbuf parity-double-buffered (one barrier/step).
// Scale fixup: q-chunk [32q,32q+32) is produced entirely by wave q>>1, so
// one factor exp(w[q>>1]-w[0]) per thread, applied before the quad combine.
// Dropped per-row constants die in the final log_softmax.
// ---------------------------------------------------------------------------
__global__ __launch_bounds__(128, 2)
void scan_kernel(const float* __restrict__ u,
                 const float* __restrict__ Pm,
                 const float* __restrict__ PT,
                 float* __restrict__ alpha,
                 float* __restrict__ beta) {
    const int t  = threadIdx.x;   // 0..127
    const int q  = t & 3;
    const int g  = t >> 2;        // 0..31
    const int j4 = g << 2;        // first of 4 owned states

    const int  id  = blockIdx.x;
    const bool fwd = id < BB * NCH;
    const int  r   = fwd ? id : id - BB * NCH;
    const int  b   = r >> 5;             // NCH = 32
    const int  c   = r & (NCH - 1);

    __shared__ alignas(16) float ebuf[2][4 * EST];
    __shared__ alignas(16) float wbuf[2][2];

    // P fragment: rows j4..j4+3 of G = (fwd ? PT : P), i-chunk [32q, 32q+32).
    f2 pf[4][16];
    {
        const float* gbase = fwd ? PT : Pm;
#pragma unroll
        for (int rr = 0; rr < 4; ++rr) {
            const float4* grow = (const float4*)(gbase + (j4 + rr) * CC + q * 32);
#pragma unroll
            for (int p_ = 0; p_ < 8; ++p_) {
                float4 v = grow[p_];
                pf[rr][2 * p_ + 0] = f2{v.x, v.y};
                pf[rr][2 * p_ + 1] = f2{v.z, v.w};
            }
        }
    }

    const float* ub = u + (size_t)b * TT * CC;
    float*       ob = (fwd ? alpha : beta) + (size_t)b * TT * CC;

    const int wlo = c * LCH;
    const int whi = wlo + LCH;
    int t0 = 0, t1 = 0, NS;
    if (fwd) {
        t0 = wlo - WCH; if (t0 < 0) t0 = 0;
        NS = whi - 1 - t0;
    } else {
        t1 = whi - 1 + WCH; if (t1 > TT - 1) t1 = TT - 1;
        NS = t1 - wlo;
    }

    // Per-thread state for 4 states (4 redundant q-copies each).
    float4 st, u_cur, u_n1, u_n2, u_pf;
    if (fwd) {
        st = *(const float4*)(ub + t0 * CC + j4);           // exact when t0==0
        if (q == 0 && t0 == 0 && wlo == 0) *(float4*)(ob + j4) = st;
        u_cur = *(const float4*)(ub + (t0 + 1) * CC + j4);
        u_n1  = *(const float4*)(ub + (t0 + 2) * CC + j4);
        u_n2  = *(const float4*)(ub + (t0 + 3) * CC + j4);
    } else {
        st = float4{0.f, 0.f, 0.f, 0.f};                    // exact when t1==TT-1
        if (q == 0 && t1 == whi - 1) *(float4*)(ob + t1 * CC + j4) = st;
        u_cur = *(const float4*)(ub + (t1    ) * CC + j4);
        u_n1  = *(const float4*)(ub + (t1 - 1) * CC + j4);
        u_n2  = *(const float4*)(ub + (t1 - 2) * CC + j4);
    }

    const int epos = (g >> 3) * EST + (g & 7) * 4;  // padded float4 slot

    for (int s = 0; s < NS; ++s) {
        const int par = s & 1;

        // prefetch u row for step s+3 (clamped; extra loads harmless)
        int rpf;
        if (fwd) { rpf = t0 + 4 + s; if (rpf > TT - 1) rpf = TT - 1; }
        else     { rpf = t1 - 3 - s; if (rpf < 0)      rpf = 0; }
        u_pf = *(const float4*)(ub + rpf * CC + j4);

        // fwd: x = alpha_{t-1};  bwd: x = beta_{t+1} + u_{t+1}
        float4 x;
        if (fwd) x = st;
        else     x = float4{st.x + u_cur.x, st.y + u_cur.y,
                            st.z + u_cur.z, st.w + u_cur.w};
        float w = __int_as_float(__builtin_amdgcn_readfirstlane(__float_as_int(x.x)));
        float4 e;
        e.x = __expf(x.x - w);
        e.y = __expf(x.y - w);
        e.z = __expf(x.z - w);
        e.w = __expf(x.w - w);
        if (q == 0) *(float4*)(&ebuf[par][epos]) = e;
        if ((t & 63) == 0) wbuf[par][t >> 6] = w;
        lds_barrier();  // e + w published (the ONLY barrier this step)

        // 4 dots over i in [32q, 32q+32): 8 broadcast b128 reads reused x4
        const float4* ec = (const float4*)(&ebuf[par][q * EST]);
        f2 a0[4], a1[4];
#pragma unroll
        for (int rr = 0; rr < 4; ++rr) { a0[rr] = f2{0.f, 0.f}; a1[rr] = f2{0.f, 0.f}; }
#pragma unroll
        for (int p_ = 0; p_ < 8; ++p_) {
            float4 ev = ec[p_];
            f2 e01 = f2{ev.x, ev.y};
            f2 e23 = f2{ev.z, ev.w};
#pragma unroll
            for (int rr = 0; rr < 4; ++rr) {
                a0[rr] = __builtin_elementwise_fma(e01, pf[rr][2 * p_ + 0], a0[rr]);
                a1[rr] = __builtin_elementwise_fma(e23, pf[rr][2 * p_ + 1], a1[rr]);
            }
        }

        // scale fixup: this thread's whole i-chunk was produced by wave q>>1
        f2    wpair = *((const f2*)&wbuf[par][0]);
        float wg = (q >= 2) ? wpair.y : wpair.x;
        float fs = __expf(wg - wpair.x);   // == 1.0 for q<2

        float4 sp;
        { f2 s2 = a0[0] + a1[0]; sp.x = (s2.x + s2.y) * fs; }
        { f2 s2 = a0[1] + a1[1]; sp.y = (s2.x + s2.y) * fs; }
        { f2 s2 = a0[2] + a1[2]; sp.z = (s2.x + s2.y) * fs; }
        { f2 s2 = a0[3] + a1[3]; sp.w = (s2.x + s2.y) * fs; }

        // combine the 4 quarters (consecutive lanes) on the VALU pipe
        sp.x = qadd<0x4E>(qadd<0xB1>(sp.x));
        sp.y = qadd<0x4E>(qadd<0xB1>(sp.y));
        sp.z = qadd<0x4E>(qadd<0xB1>(sp.z));
        sp.w = qadd<0x4E>(qadd<0xB1>(sp.w));

        float4 L;
        L.x = __logf(sp.x);
        L.y = __logf(sp.y);
        L.z = __logf(sp.z);
        L.w = __logf(sp.w);
        if (fwd) st = float4{u_cur.x + L.x, u_cur.y + L.y,
                             u_cur.z + L.z, u_cur.w + L.w};
        else     st = L;

        int  trow = fwd ? (t0 + 1 + s) : (t1 - 1 - s);
        bool wr   = fwd ? (trow >= wlo) : (trow < whi);
        if (q == 0 && wr) *(float4*)(ob + trow * CC + j4) = st;

        u_cur = u_n1; u_n1 = u_n2; u_n2 = u_pf;
    }
}

// ---------------------------------------------------------------------------
// Combine: out = log_softmax(alpha + beta, axis=-1), in place over d_out.
// float4 per lane; each 32-lane half-wave owns one row (128 floats).
// ---------------------------------------------------------------------------
__global__ __launch_bounds__(256) void combine_kernel(float* __restrict__ out,
                                                      const float* __restrict__ beta) {
    const int    lane = threadIdx.x & 63;
    const int    li   = lane & 31;
    const size_t row  = (size_t)blockIdx.x * 8 + ((threadIdx.x >> 6) << 1) + (lane >> 5);

    float4*       o4 = (float4*)(out + row * CC);
    const float4* b4 = (const float4*)(beta + row * CC);

    float4 a = o4[li];
    float4 bb = b4[li];
    float4 z = float4{a.x + bb.x, a.y + bb.y, a.z + bb.z, a.w + bb.w};

    float m = fmaxf(fmaxf(z.x, z.y), fmaxf(z.z, z.w));
#pragma unroll
    for (int o = 1; o < 32; o <<= 1) m = fmaxf(m, __shfl_xor(m, o, 64));
    float s = __expf(z.x - m) + __expf(z.y - m) + __expf(z.z - m) + __expf(z.w - m);
#pragma unroll
    for (int o = 1; o < 32; o <<= 1) s += __shfl_xor(s, o, 64);
    float ls = m + __logf(s);
    o4[li] = float4{z.x - ls, z.y - ls, z.z - ls, z.w - ls};
}

// ---------------------------------------------------------------------------
extern "C" void kernel_launch(void* const* d_in, const int* in_sizes, int n_in,
                              void* d_out, int out_size, void* d_ws, size_t ws_size,
                              hipStream_t stream) {
    const float* u_in = (const float*)d_in[0];   // (B, T, C) fp32
    const float* lt   = (const float*)d_in[1];   // (C, C)    fp32
    float*       out  = (float*)d_out;           // (B, T, C) fp32

    float* P    = (float*)d_ws;
    float* PT   = P + CC * CC;
    float* beta = PT + CC * CC;

    prep_kernel<<<CC, CC, 0, stream>>>(lt, P, PT);
    scan_kernel<<<2 * BB * NCH, 128, 0, stream>>>(u_in, P, PT, out, beta);
    combine_kernel<<<(BB * TT) / 8, 256, 0, stream>>>(out, beta);
}

// Round 2
// 269.993 us; speedup vs baseline: 1.1629x; 1.0082x over previous
//
#include <hip/hip_runtime.h>
#include <math.h>

#define BB 16
#define TT 4096
#define CC 128

// Chunked scan: L-sized output chunks, W-step cold-start warmup (proven
// R7/R8/R9 structure: absmax bit-identical 0.0625 at W=512/384/96; W=48
// keeps >2x empirical margin).
//
// R11 change: pf as 64 NAMED f2 SSA values (macro-generated), not an array.
// R10's `f2 pf[4][16]` failed SROA -> scratch/cache: VGPR_Count=92 proved
// the 128-float P-fragment was re-read every step (512 B/thread/step ->
// 256 KB/CU/step through L1/L2 ~= 1900 cyc/step, the dominant cost).
// Named SSA values are guaranteed mem2reg'd; expected ~200 VGPR, which fits
// launch_bounds(128,2)'s 256-cap (2 waves/SIMD, 4 blocks/CU, grid=1024).
#define LCH 128
#define WCH 48
#define NCH (TT / LCH)   // 32 chunks per chain

// Padded e-chunk stride: 36 floats (144 B) staggers the 4 broadcast read
// addresses across banks 0/4/8/12 (R6->R7: conflicts 1.28e8 -> 0).
#define EST 36

typedef float f2 __attribute__((ext_vector_type(2)));

// ---------------------------------------------------------------------------
// ws layout (floats):
//   [0,            CC*CC)              P   (row-major, softmax(log_trans) rows)
//   [CC*CC,        2*CC*CC)            PT  (transpose of P)
//   [2*CC*CC,      2*CC*CC + BB*TT*CC) beta
// ---------------------------------------------------------------------------

__device__ __forceinline__ float wave_reduce_max(float v) {
#pragma unroll
    for (int o = 1; o < 64; o <<= 1) v = fmaxf(v, __shfl_xor(v, o, 64));
    return v;
}
__device__ __forceinline__ float wave_reduce_sum(float v) {
#pragma unroll
    for (int o = 1; o < 64; o <<= 1) v += __shfl_xor(v, o, 64);
    return v;
}

// LDS-only barrier: skip the compiler's conservative s_waitcnt vmcnt(0)
// before s_barrier so global prefetch/stores stay in flight.
__device__ __forceinline__ void lds_barrier() {
    __asm__ __volatile__("s_waitcnt lgkmcnt(0)" ::: "memory");
    __builtin_amdgcn_s_barrier();
}

// Quad-perm butterfly add via DPP: cross-lane xor over lane bits 0-1 on the
// VALU pipe. 0xB1 = quad_perm(1,0,3,2) (xor 1), 0x4E = quad_perm(2,3,0,1).
template <int CTRL>
__device__ __forceinline__ float qadd(float v) {
    int o = __builtin_amdgcn_update_dpp(0, __float_as_int(v), CTRL, 0xF, 0xF, true);
    return v + __int_as_float(o);
}

// ---- pf: 4 rows x 16 f2 as NAMED values (no array -> guaranteed VGPRs) ----
#define PF_DECL(rr)                                                            \
    f2 pf_##rr##_0, pf_##rr##_1, pf_##rr##_2, pf_##rr##_3, pf_##rr##_4,        \
        pf_##rr##_5, pf_##rr##_6, pf_##rr##_7, pf_##rr##_8, pf_##rr##_9,       \
        pf_##rr##_10, pf_##rr##_11, pf_##rr##_12, pf_##rr##_13, pf_##rr##_14,  \
        pf_##rr##_15

#define PF_LOAD(rr)                                                            \
    do {                                                                       \
        const float4* grow =                                                   \
            (const float4*)(gbase + (j4 + rr) * CC + q * 32);                  \
        float4 v;                                                              \
        v = grow[0]; pf_##rr##_0  = f2{v.x, v.y}; pf_##rr##_1  = f2{v.z, v.w}; \
        v = grow[1]; pf_##rr##_2  = f2{v.x, v.y}; pf_##rr##_3  = f2{v.z, v.w}; \
        v = grow[2]; pf_##rr##_4  = f2{v.x, v.y}; pf_##rr##_5  = f2{v.z, v.w}; \
        v = grow[3]; pf_##rr##_6  = f2{v.x, v.y}; pf_##rr##_7  = f2{v.z, v.w}; \
        v = grow[4]; pf_##rr##_8  = f2{v.x, v.y}; pf_##rr##_9  = f2{v.z, v.w}; \
        v = grow[5]; pf_##rr##_10 = f2{v.x, v.y}; pf_##rr##_11 = f2{v.z, v.w}; \
        v = grow[6]; pf_##rr##_12 = f2{v.x, v.y}; pf_##rr##_13 = f2{v.z, v.w}; \
        v = grow[7]; pf_##rr##_14 = f2{v.x, v.y}; pf_##rr##_15 = f2{v.z, v.w}; \
    } while (0)

// Dot of row rr against the 32-float e-chunk: two 8-deep fma chains (aA, aB),
// all operands compile-time-named -> stays in registers.
#define ROW_DOT(rr, OUT)                                                       \
    do {                                                                       \
        f2 aA = __builtin_elementwise_fma(e01_0, pf_##rr##_0, f2{0.f, 0.f});   \
        f2 aB = __builtin_elementwise_fma(e23_0, pf_##rr##_1, f2{0.f, 0.f});   \
        aA = __builtin_elementwise_fma(e01_1, pf_##rr##_2, aA);                \
        aB = __builtin_elementwise_fma(e23_1, pf_##rr##_3, aB);                \
        aA = __builtin_elementwise_fma(e01_2, pf_##rr##_4, aA);                \
        aB = __builtin_elementwise_fma(e23_2, pf_##rr##_5, aB);                \
        aA = __builtin_elementwise_fma(e01_3, pf_##rr##_6, aA);                \
        aB = __builtin_elementwise_fma(e23_3, pf_##rr##_7, aB);                \
        aA = __builtin_elementwise_fma(e01_4, pf_##rr##_8, aA);                \
        aB = __builtin_elementwise_fma(e23_4, pf_##rr##_9, aB);                \
        aA = __builtin_elementwise_fma(e01_5, pf_##rr##_10, aA);               \
        aB = __builtin_elementwise_fma(e23_5, pf_##rr##_11, aB);               \
        aA = __builtin_elementwise_fma(e01_6, pf_##rr##_12, aA);               \
        aB = __builtin_elementwise_fma(e23_6, pf_##rr##_13, aB);               \
        aA = __builtin_elementwise_fma(e01_7, pf_##rr##_14, aA);               \
        aB = __builtin_elementwise_fma(e23_7, pf_##rr##_15, aB);               \
        f2 s2 = aA + aB;                                                       \
        OUT = (s2.x + s2.y) * fs;                                              \
    } while (0)

// ---------------------------------------------------------------------------
// Prep: P = exp(log_softmax(log_trans, axis=1)); also PT = P^T.
// ---------------------------------------------------------------------------
__global__ __launch_bounds__(CC) void prep_kernel(const float* __restrict__ lt,
                                                  float* __restrict__ P,
                                                  float* __restrict__ PT) {
    const int r  = blockIdx.x;
    const int j  = threadIdx.x;
    const int wv = j >> 6;
    __shared__ float sm[2];

    float x = lt[r * CC + j];
    float m = wave_reduce_max(x);
    if ((j & 63) == 0) sm[wv] = m;
    __syncthreads();
    m = fmaxf(sm[0], sm[1]);
    __syncthreads();
    float e = __expf(x - m);
    float s = wave_reduce_sum(e);
    if ((j & 63) == 0) sm[wv] = s;
    __syncthreads();
    s = sm[0] + sm[1];
    float p = e / s;
    P[r * CC + j]  = p;
    PT[j * CC + r] = p;
}

// ---------------------------------------------------------------------------
// Chunked scan, ONE barrier per step.
// Grid = 2*BB*NCH blocks of 128 threads (2 waves).
//   id < BB*NCH  : forward chunk  (alpha -> d_out)
//   id >= BB*NCH : backward chunk (beta  -> ws)
// Thread t: quarter q = t&3 (i-range [32q,32q+32)), group g = t>>2 owning
// states 4g..4g+3. The 4 q-copies of a group are consecutive lanes -> DPP
// quad combine. e stored padded: group g at ebuf[(g>>3)*EST + (g&7)*4]
// (float4 write by q==0). ebuf/wbuf parity-double-buffered (1 barrier/step).
// Scale fixup: q-chunk [32q,32q+32) is produced entirely by wave q>>1, so
// one factor exp(w[q>>1]-w[0]) per thread, applied before the quad combine.
// Dropped per-row constants die in the final log_softmax.
// ---------------------------------------------------------------------------
__global__ __launch_bounds__(128, 2)
void scan_kernel(const float* __restrict__ u,
                 const float* __restrict__ Pm,
                 const float* __restrict__ PT,
                 float* __restrict__ alpha,
                 float* __restrict__ beta) {
    const int t  = threadIdx.x;   // 0..127
    const int q  = t & 3;
    const int g  = t >> 2;        // 0..31
    const int j4 = g << 2;        // first of 4 owned states

    const int  id  = blockIdx.x;
    const bool fwd = id < BB * NCH;
    const int  r   = fwd ? id : id - BB * NCH;
    const int  b   = r >> 5;             // NCH = 32
    const int  c   = r & (NCH - 1);

    __shared__ alignas(16) float ebuf[2][4 * EST];
    __shared__ alignas(16) float wbuf[2][2];

    // P fragment: rows j4..j4+3 of G = (fwd ? PT : P), i-chunk [32q, 32q+32).
    PF_DECL(0); PF_DECL(1); PF_DECL(2); PF_DECL(3);
    {
        const float* gbase = fwd ? PT : Pm;
        PF_LOAD(0); PF_LOAD(1); PF_LOAD(2); PF_LOAD(3);
    }

    const float* ub = u + (size_t)b * TT * CC;
    float*       ob = (fwd ? alpha : beta) + (size_t)b * TT * CC;

    const int wlo = c * LCH;
    const int whi = wlo + LCH;
    int t0 = 0, t1 = 0, NS;
    if (fwd) {
        t0 = wlo - WCH; if (t0 < 0) t0 = 0;
        NS = whi - 1 - t0;
    } else {
        t1 = whi - 1 + WCH; if (t1 > TT - 1) t1 = TT - 1;
        NS = t1 - wlo;
    }

    // Per-thread state for 4 states (4 redundant q-copies each).
    float4 st, u_cur, u_n1, u_n2, u_pf;
    if (fwd) {
        st = *(const float4*)(ub + t0 * CC + j4);           // exact when t0==0
        if (q == 0 && t0 == 0 && wlo == 0) *(float4*)(ob + j4) = st;
        u_cur = *(const float4*)(ub + (t0 + 1) * CC + j4);
        u_n1  = *(const float4*)(ub + (t0 + 2) * CC + j4);
        u_n2  = *(const float4*)(ub + (t0 + 3) * CC + j4);
    } else {
        st = float4{0.f, 0.f, 0.f, 0.f};                    // exact when t1==TT-1
        if (q == 0 && t1 == whi - 1) *(float4*)(ob + t1 * CC + j4) = st;
        u_cur = *(const float4*)(ub + (t1    ) * CC + j4);
        u_n1  = *(const float4*)(ub + (t1 - 1) * CC + j4);
        u_n2  = *(const float4*)(ub + (t1 - 2) * CC + j4);
    }

    const int epos = (g >> 3) * EST + (g & 7) * 4;  // padded float4 slot

    for (int s = 0; s < NS; ++s) {
        const int par = s & 1;

        // prefetch u row for step s+3 (clamped; extra loads harmless)
        int rpf;
        if (fwd) { rpf = t0 + 4 + s; if (rpf > TT - 1) rpf = TT - 1; }
        else     { rpf = t1 - 3 - s; if (rpf < 0)      rpf = 0; }
        u_pf = *(const float4*)(ub + rpf * CC + j4);

        // fwd: x = alpha_{t-1};  bwd: x = beta_{t+1} + u_{t+1}
        float4 x;
        if (fwd) x = st;
        else     x = float4{st.x + u_cur.x, st.y + u_cur.y,
                            st.z + u_cur.z, st.w + u_cur.w};
        float w = __int_as_float(__builtin_amdgcn_readfirstlane(__float_as_int(x.x)));
        float4 e;
        e.x = __expf(x.x - w);
        e.y = __expf(x.y - w);
        e.z = __expf(x.z - w);
        e.w = __expf(x.w - w);
        if (q == 0) *(float4*)(&ebuf[par][epos]) = e;
        if ((t & 63) == 0) wbuf[par][t >> 6] = w;
        lds_barrier();  // e + w published (the ONLY barrier this step)

        // broadcast-read the 32-float e-chunk for quarter q (8 b128, banks
        // staggered by EST padding -> conflict-free)
        const float4* ec = (const float4*)(&ebuf[par][q * EST]);
        float4 ev0 = ec[0], ev1 = ec[1], ev2 = ec[2], ev3 = ec[3];
        float4 ev4 = ec[4], ev5 = ec[5], ev6 = ec[6], ev7 = ec[7];
        f2 e01_0 = f2{ev0.x, ev0.y}, e23_0 = f2{ev0.z, ev0.w};
        f2 e01_1 = f2{ev1.x, ev1.y}, e23_1 = f2{ev1.z, ev1.w};
        f2 e01_2 = f2{ev2.x, ev2.y}, e23_2 = f2{ev2.z, ev2.w};
        f2 e01_3 = f2{ev3.x, ev3.y}, e23_3 = f2{ev3.z, ev3.w};
        f2 e01_4 = f2{ev4.x, ev4.y}, e23_4 = f2{ev4.z, ev4.w};
        f2 e01_5 = f2{ev5.x, ev5.y}, e23_5 = f2{ev5.z, ev5.w};
        f2 e01_6 = f2{ev6.x, ev6.y}, e23_6 = f2{ev6.z, ev6.w};
        f2 e01_7 = f2{ev7.x, ev7.y}, e23_7 = f2{ev7.z, ev7.w};

        // scale fixup: this thread's whole i-chunk was produced by wave q>>1
        f2    wpair = *((const f2*)&wbuf[par][0]);
        float wg = (q >= 2) ? wpair.y : wpair.x;
        float fs = __expf(wg - wpair.x);   // == 1.0 for q<2

        float4 sp;
        ROW_DOT(0, sp.x);
        ROW_DOT(1, sp.y);
        ROW_DOT(2, sp.z);
        ROW_DOT(3, sp.w);

        // combine the 4 quarters (consecutive lanes) on the VALU pipe
        sp.x = qadd<0x4E>(qadd<0xB1>(sp.x));
        sp.y = qadd<0x4E>(qadd<0xB1>(sp.y));
        sp.z = qadd<0x4E>(qadd<0xB1>(sp.z));
        sp.w = qadd<0x4E>(qadd<0xB1>(sp.w));

        float4 L;
        L.x = __logf(sp.x);
        L.y = __logf(sp.y);
        L.z = __logf(sp.z);
        L.w = __logf(sp.w);
        if (fwd) st = float4{u_cur.x + L.x, u_cur.y + L.y,
                             u_cur.z + L.z, u_cur.w + L.w};
        else     st = L;

        int  trow = fwd ? (t0 + 1 + s) : (t1 - 1 - s);
        bool wr   = fwd ? (trow >= wlo) : (trow < whi);
        if (q == 0 && wr) *(float4*)(ob + trow * CC + j4) = st;

        u_cur = u_n1; u_n1 = u_n2; u_n2 = u_pf;
    }
}

// ---------------------------------------------------------------------------
// Combine: out = log_softmax(alpha + beta, axis=-1), in place over d_out.
// float4 per lane; each 32-lane half-wave owns one row (128 floats).
// ---------------------------------------------------------------------------
__global__ __launch_bounds__(256) void combine_kernel(float* __restrict__ out,
                                                      const float* __restrict__ beta) {
    const int    lane = threadIdx.x & 63;
    const int    li   = lane & 31;
    const size_t row  = (size_t)blockIdx.x * 8 + ((threadIdx.x >> 6) << 1) + (lane >> 5);

    float4*       o4 = (float4*)(out + row * CC);
    const float4* b4 = (const float4*)(beta + row * CC);

    float4 a = o4[li];
    float4 bb = b4[li];
    float4 z = float4{a.x + bb.x, a.y + bb.y, a.z + bb.z, a.w + bb.w};

    float m = fmaxf(fmaxf(z.x, z.y), fmaxf(z.z, z.w));
#pragma unroll
    for (int o = 1; o < 32; o <<= 1) m = fmaxf(m, __shfl_xor(m, o, 64));
    float s = __expf(z.x - m) + __expf(z.y - m) + __expf(z.z - m) + __expf(z.w - m);
#pragma unroll
    for (int o = 1; o < 32; o <<= 1) s += __shfl_xor(s, o, 64);
    float ls = m + __logf(s);
    o4[li] = float4{z.x - ls, z.y - ls, z.z - ls, z.w - ls};
}

// ---------------------------------------------------------------------------
extern "C" void kernel_launch(void* const* d_in, const int* in_sizes, int n_in,
                              void* d_out, int out_size, void* d_ws, size_t ws_size,
                              hipStream_t stream) {
    const float* u_in = (const float*)d_in[0];   // (B, T, C) fp32
    const float* lt   = (const float*)d_in[1];   // (C, C)    fp32
    float*       out  = (float*)d_out;           // (B, T, C) fp32

    float* P    = (float*)d_ws;
    float* PT   = P + CC * CC;
    float* beta = PT + CC * CC;

    prep_kernel<<<CC, CC, 0, stream>>>(lt, P, PT);
    scan_kernel<<<2 * BB * NCH, 128, 0, stream>>>(u_in, P, PT, out, beta);
    combine_kernel<<<(BB * TT) / 8, 256, 0, stream>>>(out, beta);
}